// Round 3
// baseline (2889.420 us; speedup 1.0000x reference)
//
#include <hip/hip_runtime.h>
#include <hip/hip_bf16.h>

// Problem constants (GeoUmpForPretrain) — all tensors fp32 per reference.
constexpr int B = 16, S = 512, H = 768, T = 2, N = 32, L = 64, E = 8, D = 128, A = 128;
constexpr float INV_SQRT_D = 0.08838834764831843f;  // 1/sqrt(128)

// ---------------------------------------------------------------------------
// K1: gather entity spans -> e_fea [B,T,E,H], feas = mean over E [B,T,H]
__global__ void k_gather(const float* __restrict__ xs,
                         const int* __restrict__ spans,
                         float* __restrict__ e_fea, float* __restrict__ feas) {
    int bt = blockIdx.x;            // b*T + t
    int b = bt / T;
    int span = spans[bt];
    for (int h = threadIdx.x; h < H; h += 256) {
        float acc = 0.f;
        for (int e = 0; e < E; e++) {
            float v = xs[((size_t)b * S + span + e) * H + h];
            e_fea[((size_t)bt * E + e) * H + h] = v;
            acc += v;
        }
        feas[(size_t)bt * H + h] = acc * (1.0f / E);
    }
}

// ---------------------------------------------------------------------------
// K2: q = e_fea @ Wq + bq   [B*T*E, D]
__global__ void k_qproj(const float* __restrict__ e_fea,
                        const float* __restrict__ Wq,
                        const float* __restrict__ bq,
                        float* __restrict__ q) {
    int row = blockIdx.x;           // over B*T*E
    int d = threadIdx.x;            // 0..127
    const float* er = e_fea + (size_t)row * H;
    float acc = bq[d];
    #pragma unroll 4
    for (int h = 0; h < H; h++) acc += er[h] * Wq[(size_t)h * D + d];
    q[(size_t)row * D + d] = acc;
}

// ---------------------------------------------------------------------------
// K3: kbuf = neigh_emb @ Wk + bk   [B*T*N*L, D]
__global__ void k_kproj(const float* __restrict__ neigh,
                        const float* __restrict__ Wk,
                        const float* __restrict__ bk,
                        float* __restrict__ kbuf) {
    int row = blockIdx.x * 2 + (threadIdx.x >> 7);   // 2 rows per block
    int d = threadIdx.x & 127;
    const float* nr = neigh + (size_t)row * H;
    float acc = bk[d];
    #pragma unroll 4
    for (int h = 0; h < H; h++) acc += nr[h] * Wk[(size_t)h * D + d];
    kbuf[(size_t)row * D + d] = acc;
}

// ---------------------------------------------------------------------------
// K4: per (b,t,n): logits = q k^T / sqrt(D); softmax over L; store probs
//     attn_p [btn,E,L]; pooled[btn,h] = (mean_e attn) @ neigh.
__global__ void k_sdpa(const float* __restrict__ q, const float* __restrict__ kbuf,
                       const float* __restrict__ neigh,
                       float* __restrict__ attn_p, float* __restrict__ pooled) {
    __shared__ float q_s[E * D];         // 4 KB
    __shared__ float k_s[L * 129];       // 33 KB, pad to dodge bank conflicts
    __shared__ float attn_s[E * L];      // 2 KB
    __shared__ float abar_s[L];
    int btn = blockIdx.x;                // (b*T+t)*N + n
    int bt = btn / N;
    const float* qrow = q + (size_t)bt * E * D;
    const float* krow = kbuf + (size_t)btn * L * D;
    const float* nrow = neigh + (size_t)btn * L * H;

    for (int i = threadIdx.x; i < E * D; i += 256) q_s[i] = qrow[i];
    for (int i = threadIdx.x; i < L * D; i += 256) {
        int l = i >> 7, d = i & 127;
        k_s[l * 129 + d] = krow[i];
    }
    __syncthreads();

    for (int p = threadIdx.x; p < E * L; p += 256) {
        int e = p >> 6, l = p & 63;
        float acc = 0.f;
        #pragma unroll 4
        for (int d = 0; d < D; d++) acc += q_s[e * D + d] * k_s[l * 129 + d];
        attn_s[e * L + l] = acc * INV_SQRT_D;
    }
    __syncthreads();

    if (threadIdx.x < E) {
        int e = threadIdx.x;
        float m = -1e30f;
        for (int l = 0; l < L; l++) m = fmaxf(m, attn_s[e * L + l]);
        float ssum = 0.f;
        for (int l = 0; l < L; l++) {
            float ex = expf(attn_s[e * L + l] - m);
            attn_s[e * L + l] = ex;
            ssum += ex;
        }
        float inv = 1.0f / ssum;
        for (int l = 0; l < L; l++) attn_s[e * L + l] *= inv;
    }
    __syncthreads();

    for (int i = threadIdx.x; i < E * L; i += 256)
        attn_p[(size_t)btn * E * L + i] = attn_s[i];
    if (threadIdx.x < L) {
        float s = 0.f;
        #pragma unroll
        for (int e = 0; e < E; e++) s += attn_s[e * L + threadIdx.x];
        abar_s[threadIdx.x] = s * (1.0f / E);
    }
    __syncthreads();

    for (int h = threadIdx.x; h < H; h += 256) {   // 3 iterations
        float acc = 0.f;
        for (int l = 0; l < L; l++) acc += abar_s[l] * nrow[(size_t)l * H + h];
        pooled[(size_t)btn * H + h] = acc;
    }
}

// ---------------------------------------------------------------------------
// K5a: fold Ww/Wa/bw/ba/wb/bb: misc[h]=Ww[h,:]@Wa_lo, misc[H+h]=Ww[h,:]@Wa_hi,
//      misc[2H]=bw@(Wa_lo+Wa_hi)+ba, misc[2H+1]=wb, misc[2H+2]=bb
__global__ void k_uv(const float* __restrict__ Ww, const float* __restrict__ bw,
                     const float* __restrict__ Wa, const float* __restrict__ ba,
                     const float* __restrict__ wb, const float* __restrict__ bb,
                     float* __restrict__ misc) {
    int h = blockIdx.x * blockDim.x + threadIdx.x;
    if (h < H) {
        float lo = 0.f, hi = 0.f;
        for (int a = 0; a < A; a++) {
            float w = Ww[(size_t)h * A + a];
            lo += w * Wa[a];
            hi += w * Wa[A + a];
        }
        misc[h] = lo;
        misc[H + h] = hi;
    }
    if (blockIdx.x == 0 && threadIdx.x == 0) {
        float c = ba[0];
        for (int a = 0; a < A; a++) c += bw[a] * (Wa[a] + Wa[A + a]);
        misc[2 * H] = c;
        misc[2 * H + 1] = wb[0];
        misc[2 * H + 2] = bb[0];
    }
}

// ---------------------------------------------------------------------------
// K5b: score[btn] = sigmoid(leaky(feas@v + pooled@u + c0) + dist*wb + bb)
__global__ void k_score(const float* __restrict__ feas, const float* __restrict__ pooled,
                        const float* __restrict__ misc, const float* __restrict__ dists,
                        float* __restrict__ score) {
    __shared__ float red[4];
    int btn = blockIdx.x;
    int bt = btn / N;
    float part = 0.f;
    for (int h = threadIdx.x; h < H; h += 256)
        part += feas[(size_t)bt * H + h] * misc[h] + pooled[(size_t)btn * H + h] * misc[H + h];
    #pragma unroll
    for (int off = 32; off > 0; off >>= 1) part += __shfl_down(part, off, 64);
    if ((threadIdx.x & 63) == 0) red[threadIdx.x >> 6] = part;
    __syncthreads();
    if (threadIdx.x == 0) {
        float tot = red[0] + red[1] + red[2] + red[3] + misc[2 * H];
        float lk = tot > 0.f ? tot : 0.01f * tot;        // leaky_relu slope 0.01
        float xatt = lk + dists[btn] * misc[2 * H + 1] + misc[2 * H + 2];
        score[btn] = 1.0f / (1.0f + expf(-xatt));
    }
}

// ---------------------------------------------------------------------------
// K6: delta[bt,e,h] += sum_{n, l in chunk} score_n * attn_p[n,e,l] * neigh[l,h]
//     grid (B*T, L/8); delta pre-zeroed; atomicAdd across l-chunks.
__global__ void k_delta(const float* __restrict__ attn_p, const float* __restrict__ score,
                        const float* __restrict__ neigh, float* __restrict__ delta) {
    __shared__ float w_s[E * 8];
    int bt = blockIdx.x, l0 = blockIdx.y * 8;
    float acc[E][3];
    #pragma unroll
    for (int e = 0; e < E; e++)
        #pragma unroll
        for (int c = 0; c < 3; c++) acc[e][c] = 0.f;
    for (int n = 0; n < N; n++) {
        int btn = bt * N + n;
        if (threadIdx.x < E * 8) {
            int e = threadIdx.x >> 3, lp = threadIdx.x & 7;
            w_s[threadIdx.x] = score[btn] * attn_p[((size_t)btn * E + e) * L + l0 + lp];
        }
        __syncthreads();
        const float* nrow = neigh + ((size_t)btn * L + l0) * H;
        for (int lp = 0; lp < 8; lp++) {
            float nv[3];
            #pragma unroll
            for (int c = 0; c < 3; c++) nv[c] = nrow[(size_t)lp * H + threadIdx.x + c * 256];
            #pragma unroll
            for (int e = 0; e < E; e++) {
                float w = w_s[e * 8 + lp];
                #pragma unroll
                for (int c = 0; c < 3; c++) acc[e][c] += w * nv[c];
            }
        }
        __syncthreads();
    }
    #pragma unroll
    for (int e = 0; e < E; e++)
        #pragma unroll
        for (int c = 0; c < 3; c++)
            atomicAdd(&delta[((size_t)bt * E + e) * H + threadIdx.x + c * 256], acc[e][c]);
}

// ---------------------------------------------------------------------------
// K7: x[b, span+e, h] += delta[bt,e,h]  (atomic: T spans may overlap)
__global__ void k_addspan(const float* __restrict__ delta, const int* __restrict__ spans,
                          float* __restrict__ x) {
    int i = blockIdx.x * 256 + threadIdx.x;   // over B*T*E*H
    int h = i % H;
    int e = (i / H) % E;
    int bt = i / (H * E);
    int b = bt / T;
    atomicAdd(&x[((size_t)b * S + spans[bt] + e) * H + h], delta[i]);
}

// ---------------------------------------------------------------------------
// K8a: q2 = x@Wq+bq, k2 = x@Wk+bk. Block: 8 rows x 256 cols (128 q | 128 k).
__global__ void k_qk2(const float* __restrict__ x,
                      const float* __restrict__ Wq, const float* __restrict__ bq,
                      const float* __restrict__ Wk, const float* __restrict__ bk,
                      float* __restrict__ q2, float* __restrict__ k2) {
    __shared__ float x_s[8 * H];   // 24 KB
    int r0 = blockIdx.x * 8;
    for (int i = threadIdx.x; i < 8 * H; i += 256) x_s[i] = x[(size_t)r0 * H + i];
    __syncthreads();
    int col = threadIdx.x;
    bool isq = col < D;
    int d = col & (D - 1);
    const float* W = isq ? Wq : Wk;
    float bias = isq ? bq[d] : bk[d];
    float acc[8];
    #pragma unroll
    for (int r = 0; r < 8; r++) acc[r] = bias;
    for (int h = 0; h < H; h++) {
        float w = W[(size_t)h * D + d];
        #pragma unroll
        for (int r = 0; r < 8; r++) acc[r] += x_s[r * H + h] * w;
    }
    float* outp = isq ? q2 : k2;
    #pragma unroll
    for (int r = 0; r < 8; r++) outp[((size_t)r0 + r) * D + d] = acc[r];
}

// K8b: v2 = x@Wv+bv, written IN-PLACE over x. Each block owns rows r0..r0+7
//      exclusively: stages them in LDS, syncs, then overwrites. 3 cols/thread.
__global__ void k_v2(float* __restrict__ xv, const float* __restrict__ Wv,
                     const float* __restrict__ bv) {
    __shared__ float x_s[8 * H];   // 24 KB
    int r0 = blockIdx.x * 8;
    for (int i = threadIdx.x; i < 8 * H; i += 256) x_s[i] = xv[(size_t)r0 * H + i];
    __syncthreads();
    float acc[8][3];
    #pragma unroll
    for (int c = 0; c < 3; c++) {
        float bias = bv[threadIdx.x + c * 256];
        #pragma unroll
        for (int r = 0; r < 8; r++) acc[r][c] = bias;
    }
    for (int h = 0; h < H; h++) {
        float w[3];
        #pragma unroll
        for (int c = 0; c < 3; c++) w[c] = Wv[(size_t)h * H + threadIdx.x + c * 256];
        #pragma unroll
        for (int r = 0; r < 8; r++) {
            float xr = x_s[r * H + h];
            #pragma unroll
            for (int c = 0; c < 3; c++) acc[r][c] += xr * w[c];
        }
    }
    #pragma unroll
    for (int r = 0; r < 8; r++)
        #pragma unroll
        for (int c = 0; c < 3; c++)
            xv[((size_t)r0 + r) * H + threadIdx.x + c * 256] = acc[r][c];
}

// ---------------------------------------------------------------------------
// K9: final attention. Block: 4 query rows, full softmax over S=512 keys.
__global__ void k_attn(const float* __restrict__ q2, const float* __restrict__ k2,
                       const float* __restrict__ v2, float* __restrict__ out) {
    __shared__ float q_s[4 * D];    // 2 KB
    __shared__ float p_s[4 * S];    // 8 KB
    int blk = blockIdx.x;
    int b = blk / (S / 4);
    int s0 = (blk % (S / 4)) * 4;
    for (int i = threadIdx.x; i < 4 * D; i += 256) q_s[i] = q2[((size_t)b * S + s0) * D + i];
    __syncthreads();

    for (int idx = threadIdx.x; idx < 4 * S; idx += 256) {   // 8 iterations
        int r = idx >> 9;          // /512
        int m = idx & (S - 1);
        const float* kr = k2 + ((size_t)b * S + m) * D;
        float acc = 0.f;
        #pragma unroll 4
        for (int d = 0; d < D; d++) acc += q_s[r * D + d] * kr[d];
        p_s[r * S + m] = acc * INV_SQRT_D;
    }
    __syncthreads();

    {   // softmax: one wave per query row (block = exactly 4 waves)
        int r = threadIdx.x >> 6, lane = threadIdx.x & 63;
        float m = -1e30f;
        for (int j = lane; j < S; j += 64) m = fmaxf(m, p_s[r * S + j]);
        #pragma unroll
        for (int off = 32; off; off >>= 1) m = fmaxf(m, __shfl_xor(m, off, 64));
        float ssum = 0.f;
        for (int j = lane; j < S; j += 64) {
            float ex = expf(p_s[r * S + j] - m);
            p_s[r * S + j] = ex;
            ssum += ex;
        }
        #pragma unroll
        for (int off = 32; off; off >>= 1) ssum += __shfl_xor(ssum, off, 64);
        float inv = 1.0f / ssum;
        for (int j = lane; j < S; j += 64) p_s[r * S + j] *= inv;
    }
    __syncthreads();

    float acc[4][3];
    #pragma unroll
    for (int r = 0; r < 4; r++)
        #pragma unroll
        for (int j = 0; j < 3; j++) acc[r][j] = 0.f;
    for (int m = 0; m < S; m++) {
        const float* vr = v2 + ((size_t)b * S + m) * H;
        float vv[3];
        #pragma unroll
        for (int j = 0; j < 3; j++) vv[j] = vr[threadIdx.x + j * 256];
        #pragma unroll
        for (int r = 0; r < 4; r++) {
            float p = p_s[r * S + m];
            #pragma unroll
            for (int j = 0; j < 3; j++) acc[r][j] += p * vv[j];
        }
    }
    #pragma unroll
    for (int r = 0; r < 4; r++)
        #pragma unroll
        for (int j = 0; j < 3; j++)
            out[((size_t)b * S + s0 + r) * H + threadIdx.x + j * 256] = acc[r][j];
}

// ---------------------------------------------------------------------------
extern "C" void kernel_launch(void* const* d_in, const int* in_sizes, int n_in,
                              void* d_out, int out_size, void* d_ws, size_t ws_size,
                              hipStream_t stream) {
    const float* xs    = (const float*)d_in[0];
    const float* neigh = (const float*)d_in[1];
    const float* dists = (const float*)d_in[2];
    const int*   spans = (const int*)d_in[3];
    const float* Wq = (const float*)d_in[4];
    const float* bq = (const float*)d_in[5];
    const float* Wk = (const float*)d_in[6];
    const float* bk = (const float*)d_in[7];
    const float* Wv = (const float*)d_in[8];
    const float* bv = (const float*)d_in[9];
    const float* Ww = (const float*)d_in[10];
    const float* bw = (const float*)d_in[11];
    const float* Wa = (const float*)d_in[12];
    const float* ba = (const float*)d_in[13];
    const float* wb = (const float*)d_in[14];
    const float* bb = (const float*)d_in[15];
    float* out = (float*)d_out;

    // Workspace layout (fp32), total 10,152,960 floats = 40.6 MB.
    // R1 (8,388,608 floats): kbuf [B*T*N*L, D], dead after k_sdpa; then
    //   reused exactly as x (6,291,456) | q2 (1,048,576) | k2 (1,048,576).
    //   v2 is computed in-place over x (block-exclusive rows).
    float* ws     = (float*)d_ws;
    float* kb     = ws;                                   // 8,388,608
    float* attn_p = ws + (size_t)8388608;                 //   524,288
    float* pooled = attn_p + (size_t)B * T * N * E * L;   //   786,432
    float* delta  = pooled + (size_t)B * T * N * H;       //   196,608
    float* e_fea  = delta + (size_t)B * T * E * H;        //   196,608
    float* qb     = e_fea + (size_t)B * T * E * H;        //    32,768
    float* feas   = qb + (size_t)B * T * E * D;           //    24,576
    float* misc   = feas + (size_t)B * T * H;             //     2,048
    float* scoreb = misc + 2048;                          //     1,024
    float* x      = kb;                                   // alias (kb dead)
    float* q2     = kb + (size_t)B * S * H;               // alias
    float* k2     = q2 + (size_t)B * S * D;               // alias
    float* v2     = x;                                    // in-place

    k_gather<<<B * T, 256, 0, stream>>>(xs, spans, e_fea, feas);
    k_qproj<<<B * T * E, D, 0, stream>>>(e_fea, Wq, bq, qb);
    k_kproj<<<B * T * N * L / 2, 256, 0, stream>>>(neigh, Wk, bk, kb);
    k_sdpa<<<B * T * N, 256, 0, stream>>>(qb, kb, neigh, attn_p, pooled);
    k_uv<<<3, 256, 0, stream>>>(Ww, bw, Wa, ba, wb, bb, misc);
    k_score<<<B * T * N, 256, 0, stream>>>(feas, pooled, misc, dists, scoreb);
    hipMemsetAsync(delta, 0, (size_t)B * T * E * H * sizeof(float), stream);
    k_delta<<<dim3(B * T, L / 8), 256, 0, stream>>>(attn_p, scoreb, neigh, delta);
    hipMemcpyAsync(x, xs, (size_t)B * S * H * sizeof(float), hipMemcpyDeviceToDevice, stream);
    k_addspan<<<(B * T * E * H) / 256, 256, 0, stream>>>(delta, spans, x);
    k_qk2<<<B * S / 8, 256, 0, stream>>>(x, Wq, bq, Wk, bk, q2, k2);
    k_v2<<<B * S / 8, 256, 0, stream>>>(v2, Wv, bv);
    k_attn<<<B * (S / 4), 256, 0, stream>>>(q2, k2, v2, out);
}

// Round 4
// 1650.365 us; speedup vs baseline: 1.7508x; 1.7508x over previous
//
#include <hip/hip_runtime.h>
#include <hip/hip_bf16.h>

// Problem constants (GeoUmpForPretrain) — all tensors fp32 per reference.
constexpr int B = 16, S = 512, H = 768, T = 2, N = 32, L = 64, E = 8, D = 128, A = 128;
constexpr float INV_SQRT_D = 0.08838834764831843f;  // 1/sqrt(128)

// ---------------------------------------------------------------------------
// Tiled fp32 GEMM core: C[r0:r0+128, c0:c0+128] = A @ W + bias
// A: [M,K] row-major (lda=K); W: [K,N] row-major (ldw); C row-major (ldc).
// 256 threads, 8x8 outputs/thread, BK=32. K must be a multiple of 32.
// Single call site per kernel (one LDS allocation).
__device__ __forceinline__ void gemm128(const float* __restrict__ Ap, int lda,
                                        const float* __restrict__ W, int ldw,
                                        const float* __restrict__ bias,
                                        float* __restrict__ C, int ldc,
                                        int r0, int c0, int K) {
    __shared__ float As[32][132];   // [kk][row], row-stride 132 (16B-aligned rows)
    __shared__ float Ws[32][128];   // [kk][col]
    const int tid = threadIdx.x;
    const int tr = (tid >> 4) << 3;          // 0,8,...,120
    const int tc = (tid & 15) << 3;          // 0,8,...,120
    float acc[8][8];
    #pragma unroll
    for (int i = 0; i < 8; i++)
        #pragma unroll
        for (int j = 0; j < 8; j++) acc[i][j] = 0.f;

    const int ar = tid >> 3;                 // 0..31  (A tile row base)
    const int ak = (tid & 7) << 2;           // 0..28  (A tile col, float4)
    const int wr = tid >> 5;                 // 0..7   (W tile row base)
    const int wc = (tid & 31) << 2;          // 0..124 (W tile col, float4)

    for (int k0 = 0; k0 < K; k0 += 32) {
        float4 av[4], wv[4];
        #pragma unroll
        for (int p = 0; p < 4; p++) {
            av[p] = *(const float4*)&Ap[(size_t)(r0 + ar + 32 * p) * lda + k0 + ak];
            wv[p] = *(const float4*)&W[(size_t)(k0 + wr + 8 * p) * ldw + c0 + wc];
        }
        __syncthreads();   // previous tile's LDS reads done
        #pragma unroll
        for (int p = 0; p < 4; p++) {
            As[ak + 0][ar + 32 * p] = av[p].x;
            As[ak + 1][ar + 32 * p] = av[p].y;
            As[ak + 2][ar + 32 * p] = av[p].z;
            As[ak + 3][ar + 32 * p] = av[p].w;
            *(float4*)&Ws[wr + 8 * p][wc] = wv[p];
        }
        __syncthreads();
        #pragma unroll
        for (int kk = 0; kk < 32; kk++) {
            float a[8], b[8];
            *(float4*)&a[0] = *(const float4*)&As[kk][tr];
            *(float4*)&a[4] = *(const float4*)&As[kk][tr + 4];
            *(float4*)&b[0] = *(const float4*)&Ws[kk][tc];
            *(float4*)&b[4] = *(const float4*)&Ws[kk][tc + 4];
            #pragma unroll
            for (int i = 0; i < 8; i++)
                #pragma unroll
                for (int j = 0; j < 8; j++) acc[i][j] += a[i] * b[j];
        }
    }
    #pragma unroll
    for (int i = 0; i < 8; i++) {
        float4 o0, o1;
        o0.x = acc[i][0] + bias[c0 + tc + 0];
        o0.y = acc[i][1] + bias[c0 + tc + 1];
        o0.z = acc[i][2] + bias[c0 + tc + 2];
        o0.w = acc[i][3] + bias[c0 + tc + 3];
        o1.x = acc[i][4] + bias[c0 + tc + 4];
        o1.y = acc[i][5] + bias[c0 + tc + 5];
        o1.z = acc[i][6] + bias[c0 + tc + 6];
        o1.w = acc[i][7] + bias[c0 + tc + 7];
        *(float4*)&C[(size_t)(r0 + tr + i) * ldc + c0 + tc] = o0;
        *(float4*)&C[(size_t)(r0 + tr + i) * ldc + c0 + tc + 4] = o1;
    }
}

// K3: kbuf = neigh_emb @ Wk + bk   [65536, 128]
__global__ void k_kproj(const float* __restrict__ neigh, const float* __restrict__ Wk,
                        const float* __restrict__ bk, float* __restrict__ kbuf) {
    gemm128(neigh, H, Wk, D, bk, kbuf, D, blockIdx.x * 128, 0, H);
}

// K8a: q2 = x@Wq+bq (y=0), k2 = x@Wk+bk (y=1).  grid (64, 2)
__global__ void k_qk2(const float* __restrict__ x,
                      const float* __restrict__ Wq, const float* __restrict__ bq,
                      const float* __restrict__ Wk, const float* __restrict__ bk,
                      float* __restrict__ q2, float* __restrict__ k2) {
    const float* W = blockIdx.y ? Wk : Wq;
    const float* bs = blockIdx.y ? bk : bq;
    float* C = blockIdx.y ? k2 : q2;
    gemm128(x, H, W, D, bs, C, D, blockIdx.x * 128, 0, H);
}

// ---------------------------------------------------------------------------
// K1: gather entity spans -> e_fea [B,T,E,H], feas = mean over E [B,T,H]
__global__ void k_gather(const float* __restrict__ xs,
                         const int* __restrict__ spans,
                         float* __restrict__ e_fea, float* __restrict__ feas) {
    int bt = blockIdx.x;
    int b = bt / T;
    int span = spans[bt];
    for (int h = threadIdx.x; h < H; h += 256) {
        float acc = 0.f;
        for (int e = 0; e < E; e++) {
            float v = xs[((size_t)b * S + span + e) * H + h];
            e_fea[((size_t)bt * E + e) * H + h] = v;
            acc += v;
        }
        feas[(size_t)bt * H + h] = acc * (1.0f / E);
    }
}

// ---------------------------------------------------------------------------
// K2: q = e_fea @ Wq + bq   [B*T*E, D]  (tiny: 256 rows)
__global__ void k_qproj(const float* __restrict__ e_fea,
                        const float* __restrict__ Wq,
                        const float* __restrict__ bq,
                        float* __restrict__ q) {
    int row = blockIdx.x;
    int d = threadIdx.x;
    const float* er = e_fea + (size_t)row * H;
    float acc = bq[d];
    #pragma unroll 4
    for (int h = 0; h < H; h++) acc += er[h] * Wq[(size_t)h * D + d];
    q[(size_t)row * D + d] = acc;
}

// ---------------------------------------------------------------------------
// K4: per (b,t,n): logits = q k^T / sqrt(D); softmax over L; store probs
//     attn_p [btn,E,L]; pooled[btn,h] = (mean_e attn) @ neigh.
__global__ void k_sdpa(const float* __restrict__ q, const float* __restrict__ kbuf,
                       const float* __restrict__ neigh,
                       float* __restrict__ attn_p, float* __restrict__ pooled) {
    __shared__ float q_s[E * D];
    __shared__ float k_s[L * 129];
    __shared__ float attn_s[E * L];
    __shared__ float abar_s[L];
    int btn = blockIdx.x;
    int bt = btn / N;
    const float* qrow = q + (size_t)bt * E * D;
    const float* krow = kbuf + (size_t)btn * L * D;
    const float* nrow = neigh + (size_t)btn * L * H;

    for (int i = threadIdx.x; i < E * D; i += 256) q_s[i] = qrow[i];
    for (int i = threadIdx.x; i < L * D; i += 256) {
        int l = i >> 7, d = i & 127;
        k_s[l * 129 + d] = krow[i];
    }
    __syncthreads();

    for (int p = threadIdx.x; p < E * L; p += 256) {
        int e = p >> 6, l = p & 63;
        float acc = 0.f;
        #pragma unroll 4
        for (int d = 0; d < D; d++) acc += q_s[e * D + d] * k_s[l * 129 + d];
        attn_s[e * L + l] = acc * INV_SQRT_D;
    }
    __syncthreads();

    if (threadIdx.x < E) {
        int e = threadIdx.x;
        float m = -1e30f;
        for (int l = 0; l < L; l++) m = fmaxf(m, attn_s[e * L + l]);
        float ssum = 0.f;
        for (int l = 0; l < L; l++) {
            float ex = expf(attn_s[e * L + l] - m);
            attn_s[e * L + l] = ex;
            ssum += ex;
        }
        float inv = 1.0f / ssum;
        for (int l = 0; l < L; l++) attn_s[e * L + l] *= inv;
    }
    __syncthreads();

    for (int i = threadIdx.x; i < E * L; i += 256)
        attn_p[(size_t)btn * E * L + i] = attn_s[i];
    if (threadIdx.x < L) {
        float s = 0.f;
        #pragma unroll
        for (int e = 0; e < E; e++) s += attn_s[e * L + threadIdx.x];
        abar_s[threadIdx.x] = s * (1.0f / E);
    }
    __syncthreads();

    for (int h = threadIdx.x; h < H; h += 256) {
        float acc = 0.f;
        for (int l = 0; l < L; l++) acc += abar_s[l] * nrow[(size_t)l * H + h];
        pooled[(size_t)btn * H + h] = acc;
    }
}

// ---------------------------------------------------------------------------
// K5a: fold Ww/Wa/bw/ba/wb/bb into misc
__global__ void k_uv(const float* __restrict__ Ww, const float* __restrict__ bw,
                     const float* __restrict__ Wa, const float* __restrict__ ba,
                     const float* __restrict__ wb, const float* __restrict__ bb,
                     float* __restrict__ misc) {
    int h = blockIdx.x * blockDim.x + threadIdx.x;
    if (h < H) {
        float lo = 0.f, hi = 0.f;
        for (int a = 0; a < A; a++) {
            float w = Ww[(size_t)h * A + a];
            lo += w * Wa[a];
            hi += w * Wa[A + a];
        }
        misc[h] = lo;
        misc[H + h] = hi;
    }
    if (blockIdx.x == 0 && threadIdx.x == 0) {
        float c = ba[0];
        for (int a = 0; a < A; a++) c += bw[a] * (Wa[a] + Wa[A + a]);
        misc[2 * H] = c;
        misc[2 * H + 1] = wb[0];
        misc[2 * H + 2] = bb[0];
    }
}

// ---------------------------------------------------------------------------
// K5b: score[btn] = sigmoid(leaky(feas@v + pooled@u + c0) + dist*wb + bb)
__global__ void k_score(const float* __restrict__ feas, const float* __restrict__ pooled,
                        const float* __restrict__ misc, const float* __restrict__ dists,
                        float* __restrict__ score) {
    __shared__ float red[4];
    int btn = blockIdx.x;
    int bt = btn / N;
    float part = 0.f;
    for (int h = threadIdx.x; h < H; h += 256)
        part += feas[(size_t)bt * H + h] * misc[h] + pooled[(size_t)btn * H + h] * misc[H + h];
    #pragma unroll
    for (int off = 32; off > 0; off >>= 1) part += __shfl_down(part, off, 64);
    if ((threadIdx.x & 63) == 0) red[threadIdx.x >> 6] = part;
    __syncthreads();
    if (threadIdx.x == 0) {
        float tot = red[0] + red[1] + red[2] + red[3] + misc[2 * H];
        float lk = tot > 0.f ? tot : 0.01f * tot;
        float xatt = lk + dists[btn] * misc[2 * H + 1] + misc[2 * H + 2];
        score[btn] = 1.0f / (1.0f + expf(-xatt));
    }
}

// ---------------------------------------------------------------------------
// K6: delta[bt,e,h] += sum_{n, l-chunk} score_n * attn_p[n,e,l] * neigh[l,h]
__global__ void k_delta(const float* __restrict__ attn_p, const float* __restrict__ score,
                        const float* __restrict__ neigh, float* __restrict__ delta) {
    __shared__ float w_s[E * 8];
    int bt = blockIdx.x, l0 = blockIdx.y * 8;
    float acc[E][3];
    #pragma unroll
    for (int e = 0; e < E; e++)
        #pragma unroll
        for (int c = 0; c < 3; c++) acc[e][c] = 0.f;
    for (int n = 0; n < N; n++) {
        int btn = bt * N + n;
        if (threadIdx.x < E * 8) {
            int e = threadIdx.x >> 3, lp = threadIdx.x & 7;
            w_s[threadIdx.x] = score[btn] * attn_p[((size_t)btn * E + e) * L + l0 + lp];
        }
        __syncthreads();
        const float* nrow = neigh + ((size_t)btn * L + l0) * H;
        for (int lp = 0; lp < 8; lp++) {
            float nv[3];
            #pragma unroll
            for (int c = 0; c < 3; c++) nv[c] = nrow[(size_t)lp * H + threadIdx.x + c * 256];
            #pragma unroll
            for (int e = 0; e < E; e++) {
                float w = w_s[e * 8 + lp];
                #pragma unroll
                for (int c = 0; c < 3; c++) acc[e][c] += w * nv[c];
            }
        }
        __syncthreads();
    }
    #pragma unroll
    for (int e = 0; e < E; e++)
        #pragma unroll
        for (int c = 0; c < 3; c++)
            atomicAdd(&delta[((size_t)bt * E + e) * H + threadIdx.x + c * 256], acc[e][c]);
}

// ---------------------------------------------------------------------------
// K7: x[b, span+e, h] += delta[bt,e,h]  (atomic: T spans may overlap)
__global__ void k_addspan(const float* __restrict__ delta, const int* __restrict__ spans,
                          float* __restrict__ x) {
    int i = blockIdx.x * 256 + threadIdx.x;
    int h = i % H;
    int e = (i / H) % E;
    int bt = i / (H * E);
    int b = bt / T;
    atomicAdd(&x[((size_t)b * S + spans[bt] + e) * H + h], delta[i]);
}

// ---------------------------------------------------------------------------
// K8b: v2 = x@Wv+bv IN-PLACE over x. Block owns 16 rows exclusively: stages
// them transposed in LDS (stride 20 -> aligned b128 broadcast reads), then
// overwrites. In-place safe: all global reads of own rows precede writes;
// no other block touches these rows.
__global__ void k_v2(float* __restrict__ xv, const float* __restrict__ Wv,
                     const float* __restrict__ bv) {
    __shared__ float x_s[H * 20];   // 61.4 KB, [h][r] with row-stride 20
    int r0 = blockIdx.x * 16;
    for (int i = threadIdx.x; i < 16 * H; i += 256) {
        int r = i / H, h = i - r * H;
        x_s[h * 20 + r] = xv[(size_t)r0 * H + i];
    }
    __syncthreads();
    float acc[16][3];
    #pragma unroll
    for (int c = 0; c < 3; c++) {
        float bias = bv[threadIdx.x + c * 256];
        #pragma unroll
        for (int r = 0; r < 16; r++) acc[r][c] = bias;
    }
    for (int h = 0; h < H; h++) {
        float w0 = Wv[(size_t)h * H + threadIdx.x];
        float w1 = Wv[(size_t)h * H + threadIdx.x + 256];
        float w2 = Wv[(size_t)h * H + threadIdx.x + 512];
        float xr[16];
        #pragma unroll
        for (int qq = 0; qq < 4; qq++)
            *(float4*)&xr[qq * 4] = *(const float4*)&x_s[h * 20 + qq * 4];
        #pragma unroll
        for (int r = 0; r < 16; r++) {
            acc[r][0] += xr[r] * w0;
            acc[r][1] += xr[r] * w1;
            acc[r][2] += xr[r] * w2;
        }
    }
    #pragma unroll
    for (int r = 0; r < 16; r++)
        #pragma unroll
        for (int c = 0; c < 3; c++)
            xv[((size_t)r0 + r) * H + threadIdx.x + c * 256] = acc[r][c];
}

// ---------------------------------------------------------------------------
// K9: final attention. Block: 4 query rows, full softmax over S=512 keys.
__global__ void k_attn(const float* __restrict__ q2, const float* __restrict__ k2,
                       const float* __restrict__ v2, float* __restrict__ out) {
    __shared__ float q_s[4 * D];
    __shared__ float p_s[4 * S];
    int blk = blockIdx.x;
    int b = blk / (S / 4);
    int s0 = (blk % (S / 4)) * 4;
    for (int i = threadIdx.x; i < 4 * D; i += 256) q_s[i] = q2[((size_t)b * S + s0) * D + i];
    __syncthreads();

    for (int idx = threadIdx.x; idx < 4 * S; idx += 256) {
        int r = idx >> 9;
        int m = idx & (S - 1);
        const float* kr = k2 + ((size_t)b * S + m) * D;
        float acc = 0.f;
        #pragma unroll 4
        for (int d = 0; d < D; d++) acc += q_s[r * D + d] * kr[d];
        p_s[r * S + m] = acc * INV_SQRT_D;
    }
    __syncthreads();

    {
        int r = threadIdx.x >> 6, lane = threadIdx.x & 63;
        float m = -1e30f;
        for (int j = lane; j < S; j += 64) m = fmaxf(m, p_s[r * S + j]);
        #pragma unroll
        for (int off = 32; off; off >>= 1) m = fmaxf(m, __shfl_xor(m, off, 64));
        float ssum = 0.f;
        for (int j = lane; j < S; j += 64) {
            float ex = expf(p_s[r * S + j] - m);
            p_s[r * S + j] = ex;
            ssum += ex;
        }
        #pragma unroll
        for (int off = 32; off; off >>= 1) ssum += __shfl_xor(ssum, off, 64);
        float inv = 1.0f / ssum;
        for (int j = lane; j < S; j += 64) p_s[r * S + j] *= inv;
    }
    __syncthreads();

    float acc[4][3];
    #pragma unroll
    for (int r = 0; r < 4; r++)
        #pragma unroll
        for (int j = 0; j < 3; j++) acc[r][j] = 0.f;
    for (int m = 0; m < S; m++) {
        const float* vr = v2 + ((size_t)b * S + m) * H;
        float vv[3];
        #pragma unroll
        for (int j = 0; j < 3; j++) vv[j] = vr[threadIdx.x + j * 256];
        #pragma unroll
        for (int r = 0; r < 4; r++) {
            float p = p_s[r * S + m];
            #pragma unroll
            for (int j = 0; j < 3; j++) acc[r][j] += p * vv[j];
        }
    }
    #pragma unroll
    for (int r = 0; r < 4; r++)
        #pragma unroll
        for (int j = 0; j < 3; j++)
            out[((size_t)b * S + s0 + r) * H + threadIdx.x + j * 256] = acc[r][j];
}

// ---------------------------------------------------------------------------
extern "C" void kernel_launch(void* const* d_in, const int* in_sizes, int n_in,
                              void* d_out, int out_size, void* d_ws, size_t ws_size,
                              hipStream_t stream) {
    const float* xs    = (const float*)d_in[0];
    const float* neigh = (const float*)d_in[1];
    const float* dists = (const float*)d_in[2];
    const int*   spans = (const int*)d_in[3];
    const float* Wq = (const float*)d_in[4];
    const float* bq = (const float*)d_in[5];
    const float* Wk = (const float*)d_in[6];
    const float* bk = (const float*)d_in[7];
    const float* Wv = (const float*)d_in[8];
    const float* bv = (const float*)d_in[9];
    const float* Ww = (const float*)d_in[10];
    const float* bw = (const float*)d_in[11];
    const float* Wa = (const float*)d_in[12];
    const float* ba = (const float*)d_in[13];
    const float* wb = (const float*)d_in[14];
    const float* bb = (const float*)d_in[15];
    float* out = (float*)d_out;

    // Workspace layout (fp32), total 10,152,960 floats = 40.6 MB.
    // kbuf [65536,128] dead after k_sdpa; reused as x | q2 | k2.
    // v2 computed in-place over x (block-exclusive rows).
    float* ws     = (float*)d_ws;
    float* kb     = ws;                                   // 8,388,608
    float* attn_p = ws + (size_t)8388608;                 //   524,288
    float* pooled = attn_p + (size_t)B * T * N * E * L;   //   786,432
    float* delta  = pooled + (size_t)B * T * N * H;       //   196,608
    float* e_fea  = delta + (size_t)B * T * E * H;        //   196,608
    float* qb     = e_fea + (size_t)B * T * E * H;        //    32,768
    float* feas   = qb + (size_t)B * T * E * D;           //    24,576
    float* misc   = feas + (size_t)B * T * H;             //     2,048
    float* scoreb = misc + 2048;                          //     1,024
    float* x      = kb;                                   // alias (kb dead)
    float* q2     = kb + (size_t)B * S * H;               // alias
    float* k2     = q2 + (size_t)B * S * D;               // alias
    float* v2     = x;                                    // in-place

    k_gather<<<B * T, 256, 0, stream>>>(xs, spans, e_fea, feas);
    k_qproj<<<B * T * E, D, 0, stream>>>(e_fea, Wq, bq, qb);
    k_kproj<<<B * T * N * L / 128, 256, 0, stream>>>(neigh, Wk, bk, kb);
    k_sdpa<<<B * T * N, 256, 0, stream>>>(qb, kb, neigh, attn_p, pooled);
    k_uv<<<3, 256, 0, stream>>>(Ww, bw, Wa, ba, wb, bb, misc);
    k_score<<<B * T * N, 256, 0, stream>>>(feas, pooled, misc, dists, scoreb);
    hipMemsetAsync(delta, 0, (size_t)B * T * E * H * sizeof(float), stream);
    k_delta<<<dim3(B * T, L / 8), 256, 0, stream>>>(attn_p, scoreb, neigh, delta);
    hipMemcpyAsync(x, xs, (size_t)B * S * H * sizeof(float), hipMemcpyDeviceToDevice, stream);
    k_addspan<<<(B * T * E * H) / 256, 256, 0, stream>>>(delta, spans, x);
    k_qk2<<<dim3(B * S / 128, 2), 256, 0, stream>>>(x, Wq, bq, Wk, bk, q2, k2);
    k_v2<<<B * S / 16, 256, 0, stream>>>(v2, Wv, bv);
    k_attn<<<B * (S / 4), 256, 0, stream>>>(q2, k2, v2, out);
}

// Round 5
// 1259.356 us; speedup vs baseline: 2.2944x; 1.3105x over previous
//
#include <hip/hip_runtime.h>
#include <hip/hip_bf16.h>

// Problem constants (GeoUmpForPretrain) — all tensors fp32 per reference.
constexpr int B = 16, S = 512, H = 768, T = 2, N = 32, L = 64, E = 8, D = 128, A = 128;
constexpr float INV_SQRT_D = 0.08838834764831843f;  // 1/sqrt(128)

// ---------------------------------------------------------------------------
// Tiled fp32 GEMM core: C[r0:r0+128, c0:c0+128] = A @ W (+ bias)
// A: [M,K] row-major (lda); W: [K,N] row-major (ldw); C row-major (ldc).
// 256 threads, 8x8 outputs/thread, BK=32. K must be a multiple of 32.
// bias may be nullptr. One call site per kernel (one LDS allocation).
__device__ __forceinline__ void gemm128(const float* __restrict__ Ap, int lda,
                                        const float* __restrict__ W, int ldw,
                                        const float* __restrict__ bias,
                                        float* __restrict__ C, int ldc,
                                        int r0, int c0, int K) {
    __shared__ float As[32][132];   // [kk][row], row-stride 132 (16B-aligned rows)
    __shared__ float Ws[32][128];   // [kk][col]
    const int tid = threadIdx.x;
    const int tr = (tid >> 4) << 3;          // 0,8,...,120
    const int tc = (tid & 15) << 3;          // 0,8,...,120
    float acc[8][8];
    #pragma unroll
    for (int i = 0; i < 8; i++)
        #pragma unroll
        for (int j = 0; j < 8; j++) acc[i][j] = 0.f;

    const int ar = tid >> 3;                 // 0..31  (A tile row base)
    const int ak = (tid & 7) << 2;           // 0..28  (A tile col, float4)
    const int wr = tid >> 5;                 // 0..7   (W tile row base)
    const int wc = (tid & 31) << 2;          // 0..124 (W tile col, float4)

    for (int k0 = 0; k0 < K; k0 += 32) {
        float4 av[4], wv[4];
        #pragma unroll
        for (int p = 0; p < 4; p++) {
            av[p] = *(const float4*)&Ap[(size_t)(r0 + ar + 32 * p) * lda + k0 + ak];
            wv[p] = *(const float4*)&W[(size_t)(k0 + wr + 8 * p) * ldw + c0 + wc];
        }
        __syncthreads();   // previous tile's LDS reads done
        #pragma unroll
        for (int p = 0; p < 4; p++) {
            As[ak + 0][ar + 32 * p] = av[p].x;
            As[ak + 1][ar + 32 * p] = av[p].y;
            As[ak + 2][ar + 32 * p] = av[p].z;
            As[ak + 3][ar + 32 * p] = av[p].w;
            *(float4*)&Ws[wr + 8 * p][wc] = wv[p];
        }
        __syncthreads();
        #pragma unroll
        for (int kk = 0; kk < 32; kk++) {
            float a[8], b[8];
            *(float4*)&a[0] = *(const float4*)&As[kk][tr];
            *(float4*)&a[4] = *(const float4*)&As[kk][tr + 4];
            *(float4*)&b[0] = *(const float4*)&Ws[kk][tc];
            *(float4*)&b[4] = *(const float4*)&Ws[kk][tc + 4];
            #pragma unroll
            for (int i = 0; i < 8; i++)
                #pragma unroll
                for (int j = 0; j < 8; j++) acc[i][j] += a[i] * b[j];
        }
    }
    #pragma unroll
    for (int i = 0; i < 8; i++) {
        float o[8];
        #pragma unroll
        for (int j = 0; j < 8; j++)
            o[j] = acc[i][j] + (bias ? bias[c0 + tc + j] : 0.f);
        *(float4*)&C[(size_t)(r0 + tr + i) * ldc + c0 + tc] = *(float4*)&o[0];
        *(float4*)&C[(size_t)(r0 + tr + i) * ldc + c0 + tc + 4] = *(float4*)&o[4];
    }
}

// K3: kbuf = neigh_emb @ Wk + bk   [65536, 128]
__global__ void k_kproj(const float* __restrict__ neigh, const float* __restrict__ Wk,
                        const float* __restrict__ bk, float* __restrict__ kbuf) {
    gemm128(neigh, H, Wk, D, bk, kbuf, D, blockIdx.x * 128, 0, H);
}

// K8a: q2 = x@Wq+bq (y=0), k2 = x@Wk+bk (y=1).  grid (64, 2)
__global__ void k_qk2(const float* __restrict__ x,
                      const float* __restrict__ Wq, const float* __restrict__ bq,
                      const float* __restrict__ Wk, const float* __restrict__ bk,
                      float* __restrict__ q2, float* __restrict__ k2) {
    const float* W = blockIdx.y ? Wk : Wq;
    const float* bs = blockIdx.y ? bk : bq;
    float* C = blockIdx.y ? k2 : q2;
    gemm128(x, H, W, D, bs, C, D, blockIdx.x * 128, 0, H);
}

// K9c: out[b] = P[b] @ v2[b].  grid (4, 6, 16)
__global__ void k_pv(const float* __restrict__ P, const float* __restrict__ v2,
                     float* __restrict__ out) {
    int b = blockIdx.z;
    gemm128(P + (size_t)b * S * S, S, v2 + (size_t)b * S * H, H, nullptr,
            out + (size_t)b * S * H, H, blockIdx.x * 128, blockIdx.y * 128, S);
}

// ---------------------------------------------------------------------------
// K9a: Smat[b] = q2[b] @ k2[b]^T * INV_SQRT_D.  grid (4, 4, 16).
// Both operands staged K-major in LDS (B is transposed by staging).
__global__ void k_qkT(const float* __restrict__ q2, const float* __restrict__ k2,
                      float* __restrict__ Smat) {
    __shared__ float Qs[32][132];
    __shared__ float Ks[32][132];
    const int b = blockIdx.z;
    const int r0 = blockIdx.x * 128, c0 = blockIdx.y * 128;
    const float* Qb = q2 + (size_t)b * S * D;
    const float* Kb = k2 + (size_t)b * S * D;
    float* Sb = Smat + (size_t)b * S * S;
    const int tid = threadIdx.x;
    const int tr = (tid >> 4) << 3;
    const int tc = (tid & 15) << 3;
    const int ar = tid >> 3;             // 0..31
    const int ak = (tid & 7) << 2;       // 0..28
    float acc[8][8];
    #pragma unroll
    for (int i = 0; i < 8; i++)
        #pragma unroll
        for (int j = 0; j < 8; j++) acc[i][j] = 0.f;

    for (int k0 = 0; k0 < D; k0 += 32) {
        float4 qv[4], kv[4];
        #pragma unroll
        for (int p = 0; p < 4; p++) {
            qv[p] = *(const float4*)&Qb[(size_t)(r0 + ar + 32 * p) * D + k0 + ak];
            kv[p] = *(const float4*)&Kb[(size_t)(c0 + ar + 32 * p) * D + k0 + ak];
        }
        __syncthreads();
        #pragma unroll
        for (int p = 0; p < 4; p++) {
            Qs[ak + 0][ar + 32 * p] = qv[p].x;
            Qs[ak + 1][ar + 32 * p] = qv[p].y;
            Qs[ak + 2][ar + 32 * p] = qv[p].z;
            Qs[ak + 3][ar + 32 * p] = qv[p].w;
            Ks[ak + 0][ar + 32 * p] = kv[p].x;
            Ks[ak + 1][ar + 32 * p] = kv[p].y;
            Ks[ak + 2][ar + 32 * p] = kv[p].z;
            Ks[ak + 3][ar + 32 * p] = kv[p].w;
        }
        __syncthreads();
        #pragma unroll
        for (int kk = 0; kk < 32; kk++) {
            float a[8], bb_[8];
            *(float4*)&a[0] = *(const float4*)&Qs[kk][tr];
            *(float4*)&a[4] = *(const float4*)&Qs[kk][tr + 4];
            *(float4*)&bb_[0] = *(const float4*)&Ks[kk][tc];
            *(float4*)&bb_[4] = *(const float4*)&Ks[kk][tc + 4];
            #pragma unroll
            for (int i = 0; i < 8; i++)
                #pragma unroll
                for (int j = 0; j < 8; j++) acc[i][j] += a[i] * bb_[j];
        }
    }
    #pragma unroll
    for (int i = 0; i < 8; i++) {
        float o[8];
        #pragma unroll
        for (int j = 0; j < 8; j++) o[j] = acc[i][j] * INV_SQRT_D;
        *(float4*)&Sb[(size_t)(r0 + tr + i) * S + c0 + tc] = *(float4*)&o[0];
        *(float4*)&Sb[(size_t)(r0 + tr + i) * S + c0 + tc + 4] = *(float4*)&o[4];
    }
}

// K9b: in-place row softmax on Smat. One wave per row; 4 rows/block.
__global__ void k_smax(float* __restrict__ Smat) {
    int row = blockIdx.x * 4 + (threadIdx.x >> 6);
    int lane = threadIdx.x & 63;
    float* p = Smat + (size_t)row * S;
    float4 v0 = *(const float4*)&p[lane * 4];
    float4 v1 = *(const float4*)&p[256 + lane * 4];
    float m = fmaxf(fmaxf(fmaxf(v0.x, v0.y), fmaxf(v0.z, v0.w)),
                    fmaxf(fmaxf(v1.x, v1.y), fmaxf(v1.z, v1.w)));
    #pragma unroll
    for (int off = 32; off; off >>= 1) m = fmaxf(m, __shfl_xor(m, off, 64));
    v0.x = expf(v0.x - m); v0.y = expf(v0.y - m);
    v0.z = expf(v0.z - m); v0.w = expf(v0.w - m);
    v1.x = expf(v1.x - m); v1.y = expf(v1.y - m);
    v1.z = expf(v1.z - m); v1.w = expf(v1.w - m);
    float s = v0.x + v0.y + v0.z + v0.w + v1.x + v1.y + v1.z + v1.w;
    #pragma unroll
    for (int off = 32; off; off >>= 1) s += __shfl_xor(s, off, 64);
    float inv = 1.0f / s;
    v0.x *= inv; v0.y *= inv; v0.z *= inv; v0.w *= inv;
    v1.x *= inv; v1.y *= inv; v1.z *= inv; v1.w *= inv;
    *(float4*)&p[lane * 4] = v0;
    *(float4*)&p[256 + lane * 4] = v1;
}

// ---------------------------------------------------------------------------
// K1: gather entity spans -> e_fea [B,T,E,H], feas = mean over E [B,T,H]
__global__ void k_gather(const float* __restrict__ xs,
                         const int* __restrict__ spans,
                         float* __restrict__ e_fea, float* __restrict__ feas) {
    int bt = blockIdx.x;
    int b = bt / T;
    int span = spans[bt];
    for (int h = threadIdx.x; h < H; h += 256) {
        float acc = 0.f;
        for (int e = 0; e < E; e++) {
            float v = xs[((size_t)b * S + span + e) * H + h];
            e_fea[((size_t)bt * E + e) * H + h] = v;
            acc += v;
        }
        feas[(size_t)bt * H + h] = acc * (1.0f / E);
    }
}

// ---------------------------------------------------------------------------
// K2: q = e_fea @ Wq + bq   [B*T*E, D]  (tiny: 256 rows)
__global__ void k_qproj(const float* __restrict__ e_fea,
                        const float* __restrict__ Wq,
                        const float* __restrict__ bq,
                        float* __restrict__ q) {
    int row = blockIdx.x;
    int d = threadIdx.x;
    const float* er = e_fea + (size_t)row * H;
    float acc = bq[d];
    #pragma unroll 4
    for (int h = 0; h < H; h++) acc += er[h] * Wq[(size_t)h * D + d];
    q[(size_t)row * D + d] = acc;
}

// ---------------------------------------------------------------------------
// K4: per (b,t,n): logits = q k^T / sqrt(D); softmax over L; store probs
//     attn_p [btn,E,L]; pooled[btn,h] = (mean_e attn) @ neigh.
__global__ void k_sdpa(const float* __restrict__ q, const float* __restrict__ kbuf,
                       const float* __restrict__ neigh,
                       float* __restrict__ attn_p, float* __restrict__ pooled) {
    __shared__ float q_s[E * D];
    __shared__ float k_s[L * 129];
    __shared__ float attn_s[E * L];
    __shared__ float abar_s[L];
    int btn = blockIdx.x;
    int bt = btn / N;
    const float* qrow = q + (size_t)bt * E * D;
    const float* krow = kbuf + (size_t)btn * L * D;
    const float* nrow = neigh + (size_t)btn * L * H;

    for (int i = threadIdx.x; i < E * D; i += 256) q_s[i] = qrow[i];
    for (int i = threadIdx.x; i < L * D; i += 256) {
        int l = i >> 7, d = i & 127;
        k_s[l * 129 + d] = krow[i];
    }
    __syncthreads();

    for (int p = threadIdx.x; p < E * L; p += 256) {
        int e = p >> 6, l = p & 63;
        float acc = 0.f;
        #pragma unroll 4
        for (int d = 0; d < D; d++) acc += q_s[e * D + d] * k_s[l * 129 + d];
        attn_s[e * L + l] = acc * INV_SQRT_D;
    }
    __syncthreads();

    if (threadIdx.x < E) {
        int e = threadIdx.x;
        float m = -1e30f;
        for (int l = 0; l < L; l++) m = fmaxf(m, attn_s[e * L + l]);
        float ssum = 0.f;
        for (int l = 0; l < L; l++) {
            float ex = expf(attn_s[e * L + l] - m);
            attn_s[e * L + l] = ex;
            ssum += ex;
        }
        float inv = 1.0f / ssum;
        for (int l = 0; l < L; l++) attn_s[e * L + l] *= inv;
    }
    __syncthreads();

    for (int i = threadIdx.x; i < E * L; i += 256)
        attn_p[(size_t)btn * E * L + i] = attn_s[i];
    if (threadIdx.x < L) {
        float s = 0.f;
        #pragma unroll
        for (int e = 0; e < E; e++) s += attn_s[e * L + threadIdx.x];
        abar_s[threadIdx.x] = s * (1.0f / E);
    }
    __syncthreads();

    for (int h = threadIdx.x; h < H; h += 256) {
        float acc = 0.f;
        for (int l = 0; l < L; l++) acc += abar_s[l] * nrow[(size_t)l * H + h];
        pooled[(size_t)btn * H + h] = acc;
    }
}

// ---------------------------------------------------------------------------
// K5a: fold Ww/Wa/bw/ba/wb/bb into misc
__global__ void k_uv(const float* __restrict__ Ww, const float* __restrict__ bw,
                     const float* __restrict__ Wa, const float* __restrict__ ba,
                     const float* __restrict__ wb, const float* __restrict__ bb,
                     float* __restrict__ misc) {
    int h = blockIdx.x * blockDim.x + threadIdx.x;
    if (h < H) {
        float lo = 0.f, hi = 0.f;
        for (int a = 0; a < A; a++) {
            float w = Ww[(size_t)h * A + a];
            lo += w * Wa[a];
            hi += w * Wa[A + a];
        }
        misc[h] = lo;
        misc[H + h] = hi;
    }
    if (blockIdx.x == 0 && threadIdx.x == 0) {
        float c = ba[0];
        for (int a = 0; a < A; a++) c += bw[a] * (Wa[a] + Wa[A + a]);
        misc[2 * H] = c;
        misc[2 * H + 1] = wb[0];
        misc[2 * H + 2] = bb[0];
    }
}

// ---------------------------------------------------------------------------
// K5b: score[btn] = sigmoid(leaky(feas@v + pooled@u + c0) + dist*wb + bb)
__global__ void k_score(const float* __restrict__ feas, const float* __restrict__ pooled,
                        const float* __restrict__ misc, const float* __restrict__ dists,
                        float* __restrict__ score) {
    __shared__ float red[4];
    int btn = blockIdx.x;
    int bt = btn / N;
    float part = 0.f;
    for (int h = threadIdx.x; h < H; h += 256)
        part += feas[(size_t)bt * H + h] * misc[h] + pooled[(size_t)btn * H + h] * misc[H + h];
    #pragma unroll
    for (int off = 32; off > 0; off >>= 1) part += __shfl_down(part, off, 64);
    if ((threadIdx.x & 63) == 0) red[threadIdx.x >> 6] = part;
    __syncthreads();
    if (threadIdx.x == 0) {
        float tot = red[0] + red[1] + red[2] + red[3] + misc[2 * H];
        float lk = tot > 0.f ? tot : 0.01f * tot;
        float xatt = lk + dists[btn] * misc[2 * H + 1] + misc[2 * H + 2];
        score[btn] = 1.0f / (1.0f + expf(-xatt));
    }
}

// ---------------------------------------------------------------------------
// K6: delta[bt,e,h] += sum_{n, l-chunk} score_n * attn_p[n,e,l] * neigh[l,h]
__global__ void k_delta(const float* __restrict__ attn_p, const float* __restrict__ score,
                        const float* __restrict__ neigh, float* __restrict__ delta) {
    __shared__ float w_s[E * 8];
    int bt = blockIdx.x, l0 = blockIdx.y * 8;
    float acc[E][3];
    #pragma unroll
    for (int e = 0; e < E; e++)
        #pragma unroll
        for (int c = 0; c < 3; c++) acc[e][c] = 0.f;
    for (int n = 0; n < N; n++) {
        int btn = bt * N + n;
        if (threadIdx.x < E * 8) {
            int e = threadIdx.x >> 3, lp = threadIdx.x & 7;
            w_s[threadIdx.x] = score[btn] * attn_p[((size_t)btn * E + e) * L + l0 + lp];
        }
        __syncthreads();
        const float* nrow = neigh + ((size_t)btn * L + l0) * H;
        for (int lp = 0; lp < 8; lp++) {
            float nv[3];
            #pragma unroll
            for (int c = 0; c < 3; c++) nv[c] = nrow[(size_t)lp * H + threadIdx.x + c * 256];
            #pragma unroll
            for (int e = 0; e < E; e++) {
                float w = w_s[e * 8 + lp];
                #pragma unroll
                for (int c = 0; c < 3; c++) acc[e][c] += w * nv[c];
            }
        }
        __syncthreads();
    }
    #pragma unroll
    for (int e = 0; e < E; e++)
        #pragma unroll
        for (int c = 0; c < 3; c++)
            atomicAdd(&delta[((size_t)bt * E + e) * H + threadIdx.x + c * 256], acc[e][c]);
}

// ---------------------------------------------------------------------------
// K7: x[b, span+e, h] += delta[bt,e,h]  (atomic: T spans may overlap)
__global__ void k_addspan(const float* __restrict__ delta, const int* __restrict__ spans,
                          float* __restrict__ x) {
    int i = blockIdx.x * 256 + threadIdx.x;
    int h = i % H;
    int e = (i / H) % E;
    int bt = i / (H * E);
    int b = bt / T;
    atomicAdd(&x[((size_t)b * S + spans[bt] + e) * H + h], delta[i]);
}

// ---------------------------------------------------------------------------
// K8b: v2 = x@Wv+bv IN-PLACE over x. Block owns 16 rows exclusively: stages
// them transposed in LDS, then overwrites. In-place safe.
__global__ void k_v2(float* __restrict__ xv, const float* __restrict__ Wv,
                     const float* __restrict__ bv) {
    __shared__ float x_s[H * 20];   // 61.4 KB, [h][r] with row-stride 20
    int r0 = blockIdx.x * 16;
    for (int i = threadIdx.x; i < 16 * H; i += 256) {
        int r = i / H, h = i - r * H;
        x_s[h * 20 + r] = xv[(size_t)r0 * H + i];
    }
    __syncthreads();
    float acc[16][3];
    #pragma unroll
    for (int c = 0; c < 3; c++) {
        float bias = bv[threadIdx.x + c * 256];
        #pragma unroll
        for (int r = 0; r < 16; r++) acc[r][c] = bias;
    }
    for (int h = 0; h < H; h++) {
        float w0 = Wv[(size_t)h * H + threadIdx.x];
        float w1 = Wv[(size_t)h * H + threadIdx.x + 256];
        float w2 = Wv[(size_t)h * H + threadIdx.x + 512];
        float xr[16];
        #pragma unroll
        for (int qq = 0; qq < 4; qq++)
            *(float4*)&xr[qq * 4] = *(const float4*)&x_s[h * 20 + qq * 4];
        #pragma unroll
        for (int r = 0; r < 16; r++) {
            acc[r][0] += xr[r] * w0;
            acc[r][1] += xr[r] * w1;
            acc[r][2] += xr[r] * w2;
        }
    }
    #pragma unroll
    for (int r = 0; r < 16; r++)
        #pragma unroll
        for (int c = 0; c < 3; c++)
            xv[((size_t)r0 + r) * H + threadIdx.x + c * 256] = acc[r][c];
}

// ---------------------------------------------------------------------------
extern "C" void kernel_launch(void* const* d_in, const int* in_sizes, int n_in,
                              void* d_out, int out_size, void* d_ws, size_t ws_size,
                              hipStream_t stream) {
    const float* xs    = (const float*)d_in[0];
    const float* neigh = (const float*)d_in[1];
    const float* dists = (const float*)d_in[2];
    const int*   spans = (const int*)d_in[3];
    const float* Wq = (const float*)d_in[4];
    const float* bq = (const float*)d_in[5];
    const float* Wk = (const float*)d_in[6];
    const float* bk = (const float*)d_in[7];
    const float* Wv = (const float*)d_in[8];
    const float* bv = (const float*)d_in[9];
    const float* Ww = (const float*)d_in[10];
    const float* bw = (const float*)d_in[11];
    const float* Wa = (const float*)d_in[12];
    const float* ba = (const float*)d_in[13];
    const float* wb = (const float*)d_in[14];
    const float* bb = (const float*)d_in[15];
    float* out = (float*)d_out;

    // Workspace layout (fp32), total 12,582,912 floats = 50.3 MB.
    // Region A [0, 8388608): kbuf [65536,128] (dead after k_sdpa) -> reused
    //   exactly as x (6291456) | q2 (1048576) | k2 (1048576); v2 in-place on x.
    // Region B [8388608, 12582912): early-phase smalls (attn_p..scoreb,
    //   1764352 floats, all dead before k_qkT) -> then Smat [B,S,S] (4194304).
    float* ws     = (float*)d_ws;
    float* kb     = ws;                                   // 8,388,608
    float* regB   = ws + (size_t)8388608;
    float* attn_p = regB;                                 //   524,288
    float* pooled = attn_p + (size_t)B * T * N * E * L;   //   786,432
    float* delta  = pooled + (size_t)B * T * N * H;       //   196,608
    float* e_fea  = delta + (size_t)B * T * E * H;        //   196,608
    float* qb     = e_fea + (size_t)B * T * E * H;        //    32,768
    float* feas   = qb + (size_t)B * T * E * D;           //    24,576
    float* misc   = feas + (size_t)B * T * H;             //     2,048
    float* scoreb = misc + 2048;                          //     1,024
    float* x      = kb;                                   // alias (kb dead)
    float* q2     = kb + (size_t)B * S * H;               // alias
    float* k2     = q2 + (size_t)B * S * D;               // alias
    float* v2     = x;                                    // in-place
    float* Smat   = regB;                                 // alias (smalls dead)

    k_gather<<<B * T, 256, 0, stream>>>(xs, spans, e_fea, feas);
    k_qproj<<<B * T * E, D, 0, stream>>>(e_fea, Wq, bq, qb);
    k_kproj<<<B * T * N * L / 128, 256, 0, stream>>>(neigh, Wk, bk, kb);
    k_sdpa<<<B * T * N, 256, 0, stream>>>(qb, kb, neigh, attn_p, pooled);
    k_uv<<<3, 256, 0, stream>>>(Ww, bw, Wa, ba, wb, bb, misc);
    k_score<<<B * T * N, 256, 0, stream>>>(feas, pooled, misc, dists, scoreb);
    hipMemsetAsync(delta, 0, (size_t)B * T * E * H * sizeof(float), stream);
    k_delta<<<dim3(B * T, L / 8), 256, 0, stream>>>(attn_p, scoreb, neigh, delta);
    hipMemcpyAsync(x, xs, (size_t)B * S * H * sizeof(float), hipMemcpyDeviceToDevice, stream);
    k_addspan<<<(B * T * E * H) / 256, 256, 0, stream>>>(delta, spans, x);
    k_qk2<<<dim3(B * S / 128, 2), 256, 0, stream>>>(x, Wq, bq, Wk, bk, q2, k2);
    k_v2<<<B * S / 16, 256, 0, stream>>>(v2, Wv, bv);
    k_qkT<<<dim3(S / 128, S / 128, B), 256, 0, stream>>>(q2, k2, Smat);
    k_smax<<<B * S / 4, 256, 0, stream>>>(Smat);
    k_pv<<<dim3(S / 128, H / 128, B), 256, 0, stream>>>(Smat, v2, out);
}